// Round 6
// baseline (14671.965 us; speedup 1.0000x reference)
//
#include <hip/hip_runtime.h>

// ===========================================================================
// VariationalLSTM: 3-layer bidirectional masked LSTM, B=64 T=512 Din=1024 H=512
//
//  k_cvt : fp32->fp16 elementwise converts (hidden, w_ih weights)
//  k_gemm: xg = X @ W_ih^T + bias  (fp16 MFMA 16x16x32, 128x128 tile,
//          global_load_lds staging; output layout [t][gatecol][batch] fp16)
//  k_rec : persistent bidirectional recurrence, 64 wgs (32/dir).
//          w_hh lives in VGPRs (32 x f16x8 per lane). Per step each wave
//          computes one 32x32 tile D[gaterow][batch] with mfma_32x32x16_f16;
//          gate-rows are permuted [i:8j | f:8j | g:8j | o:8j] so each lane's
//          16 acc regs = 4 gates x 4 j for ONE batch -> lane-local LSTM cell.
//          h exchanged via double-buffered hbuf [k8][batch][8] (lane-contig).
//          Step sync: h-store -> __syncthreads (drains h only) -> release
//          flag -> output stores + xg prefetch (fly during poll) ->
//          relaxed poll (wave 0) -> raw s_barrier (no drain) ->
//          acquire fence by ALL waves (each wave invalidates for itself).
// ===========================================================================

#define TT 512
#define BB 64
#define HH 512
#define G4 2048
#define DK 1024

#define AS1 __attribute__((address_space(1)))
#define AS3 __attribute__((address_space(3)))

typedef float   f32x4  __attribute__((ext_vector_type(4)));
typedef float   f32x16 __attribute__((ext_vector_type(16)));
typedef _Float16 f16x8 __attribute__((ext_vector_type(8)));
typedef _Float16 f16x4 __attribute__((ext_vector_type(4)));

__device__ __forceinline__ float fsig(float x) {
  return 1.0f / (1.0f + __expf(-x));
}
__device__ __forceinline__ float ftanhf(float x) {
  float a = fabsf(x);
  float e = __expf(-2.0f * a);
  float r = (1.0f - e) / (1.0f + e);
  return x < 0.f ? -r : r;
}

// --------------------------------------------------------------------------
// fp32 -> fp16 convert (vectorized 4-wide)
// --------------------------------------------------------------------------
__global__ __launch_bounds__(256) void k_cvt(const float* __restrict__ src,
                                             _Float16* __restrict__ dst,
                                             int n4) {
  int i = blockIdx.x * 256 + threadIdx.x;
  if (i >= n4) return;
  float4 v = reinterpret_cast<const float4*>(src)[i];
  f16x4 o;
  o[0] = (_Float16)v.x; o[1] = (_Float16)v.y;
  o[2] = (_Float16)v.z; o[3] = (_Float16)v.w;
  reinterpret_cast<f16x4*>(dst)[i] = o;
}

// --------------------------------------------------------------------------
// xg GEMM: C[m=t*64+b][n=gatecol] = X[m][k] * W[n][k] + bias[n]
// X stored [b][t][k] fp16 (row b*TT+t). Output fp16 [t][n][b].
// 128x128 tile, BK=32, 4 waves (2x2), 16x16x32 MFMA, 4x4 acc per wave.
// --------------------------------------------------------------------------
__global__ __launch_bounds__(256) void k_gemm(
    const _Float16* __restrict__ X,
    const _Float16* __restrict__ Wf, const _Float16* __restrict__ Wb,
    const float* __restrict__ bf, const float* __restrict__ bb,
    _Float16* __restrict__ of, _Float16* __restrict__ ob) {
  const _Float16* W   = blockIdx.z ? Wb : Wf;
  const float* bias   = blockIdx.z ? bb : bf;
  _Float16* out       = blockIdx.z ? ob : of;

  __shared__ _Float16 As[128 * 32];
  __shared__ _Float16 Bs[128 * 32];

  const int tid  = threadIdx.x;
  const int wave = tid >> 6;
  const int lane = tid & 63;
  const int m0 = blockIdx.x * 128;
  const int n0 = blockIdx.y * 128;
  const int wm = (wave & 1) * 64;
  const int wn = (wave >> 1) * 64;
  const int fr = lane & 15;
  const int ko = (lane >> 4) * 8;

  const int srow = wave * 16 + (lane >> 2);  // staged row within 64-chunk
  const int skh  = (lane & 3) * 8;           // k half-offset within 32

  const f32x4 z4 = {0.f, 0.f, 0.f, 0.f};
  f32x4 acc[4][4];
#pragma unroll
  for (int i = 0; i < 4; ++i)
#pragma unroll
    for (int j = 0; j < 4; ++j) acc[i][j] = z4;

  for (int k0 = 0; k0 < DK; k0 += 32) {
    __syncthreads();  // previous iter's LDS reads done
#pragma unroll
    for (int c = 0; c < 2; ++c) {
      int r  = c * 64 + srow;
      int m  = m0 + r;
      int xr = (m & 63) * TT + (m >> 6);  // b*T + t
      __builtin_amdgcn_global_load_lds(
          (const AS1 void*)(X + (size_t)xr * DK + k0 + skh),
          (AS3 void*)(As + (c * 64 + wave * 16) * 32), 16, 0, 0);
      __builtin_amdgcn_global_load_lds(
          (const AS1 void*)(W + (size_t)(n0 + r) * DK + k0 + skh),
          (AS3 void*)(Bs + (c * 64 + wave * 16) * 32), 16, 0, 0);
    }
    __syncthreads();
    f16x8 a[4], b[4];
#pragma unroll
    for (int i = 0; i < 4; ++i)
      a[i] = *reinterpret_cast<const f16x8*>(As + (wm + i * 16 + fr) * 32 + ko);
#pragma unroll
    for (int i = 0; i < 4; ++i)
      b[i] = *reinterpret_cast<const f16x8*>(Bs + (wn + i * 16 + fr) * 32 + ko);
#pragma unroll
    for (int mi = 0; mi < 4; ++mi)
#pragma unroll
      for (int ni = 0; ni < 4; ++ni)
        acc[mi][ni] = __builtin_amdgcn_mfma_f32_16x16x32_f16(
            a[mi], b[ni], acc[mi][ni], 0, 0, 0);
  }

  // epilogue: out[t][col][b] fp16, + bias
  const int t = (m0 + wm) >> 6;  // uniform per wave (wm multiple of 64)
#pragma unroll
  for (int ni = 0; ni < 4; ++ni) {
    const int col  = n0 + wn + ni * 16 + fr;
    const float bv = bias[col];
#pragma unroll
    for (int mi = 0; mi < 4; ++mi) {
      const int bl = mi * 16 + (lane >> 4) * 4;  // batch base (+reg)
      f16x4 o;
      o[0] = (_Float16)(acc[mi][ni][0] + bv);
      o[1] = (_Float16)(acc[mi][ni][1] + bv);
      o[2] = (_Float16)(acc[mi][ni][2] + bv);
      o[3] = (_Float16)(acc[mi][ni][3] + bv);
      *reinterpret_cast<f16x4*>(out + ((size_t)t * G4 + col) * BB + bl) = o;
    }
  }
}

// --------------------------------------------------------------------------
// full global barrier (used once at init; drains everything)
// --------------------------------------------------------------------------
__device__ __forceinline__ void gbar(unsigned int* flg, int wg,
                                     unsigned int target) {
  __syncthreads();
  int tid = threadIdx.x;
  if (tid < 64) {
    if (tid == 0)
      __hip_atomic_store(&flg[wg], target, __ATOMIC_RELEASE,
                         __HIP_MEMORY_SCOPE_AGENT);
    unsigned int v = target;
    for (;;) {
      if (tid < 32)
        v = __hip_atomic_load(&flg[tid], __ATOMIC_ACQUIRE,
                              __HIP_MEMORY_SCOPE_AGENT);
      if (__all(v >= target)) break;
      __builtin_amdgcn_s_sleep(1);
    }
  }
  __syncthreads();
}

// --------------------------------------------------------------------------
// persistent bidirectional recurrence for one layer
// hbuf layout: [dir][buf p][k8 = k/8][batch][k&7]  (fp16) -> B-frag loads
// are lane-contiguous (batch fast), h-writes 8B/lane.
// --------------------------------------------------------------------------
__global__ __launch_bounds__(256, 1) void k_rec(
    const float* __restrict__ whf, const float* __restrict__ whb,
    const _Float16* __restrict__ xgf, const _Float16* __restrict__ xgb,
    const int* __restrict__ seqlen,
    _Float16* __restrict__ hbuf,       // [2 dir][2 buf][HH/8][BB][8] fp16
    unsigned int* __restrict__ flags,  // [2 dir][64] u32
    _Float16* __restrict__ o16,        // [BB][TT][1024] fp16 or null
    float* __restrict__ o32) {         // [BB][TT][1024] fp32 or null
  const int wg  = blockIdx.x & 31;
  const int dir = blockIdx.x >> 5;
  const float* whh    = dir ? whb : whf;
  const _Float16* xg  = dir ? xgb : xgf;
  _Float16* hb        = hbuf + (size_t)dir * (2 * BB * HH);
  unsigned int* flg   = flags + dir * 64;

  const int tid   = threadIdx.x;
  const int wave  = tid >> 6;
  const int lane  = tid & 63;
  const int tau   = wg * 2 + (wave & 1);  // 8-wide j-slice index (0..63)
  const int btile = wave >> 1;            // 0/1 -> batches 0..31 / 32..63
  const int mrow  = lane & 31;            // A-frag row in 32-tile (perm space)
  const int hi    = lane >> 5;
  const int batch = btile * 32 + mrow;    // B-frag / acc-col batch
  // perm row -> w_hh row: gate = mrow>>3, jj = mrow&7
  const int wrow  = (mrow >> 3) * HH + tau * 8 + (mrow & 7);
  const int jb    = tau * 8 + hi * 4;     // this lane's 4 output j columns

  // ---- load w_hh fragments into registers (fp32 -> fp16), 128 VGPRs ----
  f16x8 wfrag[32];
#pragma unroll
  for (int kk = 0; kk < 32; ++kk) {
    const float* s = whh + (size_t)wrow * HH + kk * 16 + hi * 8;
    f16x8 w;
#pragma unroll
    for (int i = 0; i < 8; ++i) w[i] = (_Float16)s[i];
    wfrag[kk] = w;
  }

  const int sl = seqlen[batch];

  // zero hbuf[dir][0]: 8192 u64 per dir / 32 wgs
  reinterpret_cast<unsigned long long*>(hb)[wg * 256 + tid] = 0ull;

  float cst[4] = {0.f, 0.f, 0.f, 0.f};
  float hst[4] = {0.f, 0.f, 0.f, 0.f};

  // xg slice loader: xv[q*4+p2] = xg[t][q*HH + jb + p2][batch]
  float xv[16];
#define LOAD_XV(tt, dst)                                                     \
  {                                                                          \
    const _Float16* xgt = xg + (size_t)(tt) * (G4 * BB) + batch;             \
    _Pragma("unroll") for (int q = 0; q < 4; ++q)                            \
        _Pragma("unroll") for (int p2 = 0; p2 < 4; ++p2)                     \
            dst[q * 4 + p2] = (float)xgt[(size_t)(q * HH + jb + p2) * BB];   \
  }

  LOAD_XV(dir ? TT - 1 : 0, xv);
  gbar(flg, wg, 1u);

  for (int s = 0; s < TT; ++s) {
    const int t = dir ? (TT - 1 - s) : s;
    const int p = s & 1;

    // recurrent GEMM: acc[gaterow][batch] over K=512 (two chains)
    f32x16 acc0 = {0.f,0.f,0.f,0.f,0.f,0.f,0.f,0.f,
                   0.f,0.f,0.f,0.f,0.f,0.f,0.f,0.f};
    f32x16 acc1 = {0.f,0.f,0.f,0.f,0.f,0.f,0.f,0.f,
                   0.f,0.f,0.f,0.f,0.f,0.f,0.f,0.f};
    // B-frag: h[batch][k8*8..] at hb[p][k8][batch][0..7]; k8 = kk*2 + hi
    const _Float16* hbp = hb + (size_t)p * (BB * HH) + (size_t)batch * 8 +
                          (size_t)hi * (BB * 8);
#pragma unroll
    for (int kk = 0; kk < 32; kk += 2) {
      f16x8 h0 = *reinterpret_cast<const f16x8*>(hbp + (size_t)kk * (2 * BB * 8));
      f16x8 h1 = *reinterpret_cast<const f16x8*>(hbp + (size_t)(kk + 1) * (2 * BB * 8));
      acc0 = __builtin_amdgcn_mfma_f32_32x32x16_f16(wfrag[kk], h0, acc0, 0, 0, 0);
      acc1 = __builtin_amdgcn_mfma_f32_32x32x16_f16(wfrag[kk + 1], h1, acc1, 0, 0, 0);
    }
    f32x16 acc = acc0 + acc1;

    // ---- LSTM cell (lane-local: 4 gates x 4 j for one batch) ----
    const bool valid = t < sl;
    float ov[4];
#pragma unroll
    for (int p2 = 0; p2 < 4; ++p2) {
      float pi = acc[p2]      + xv[p2];
      float pf = acc[4 + p2]  + xv[4 + p2];
      float pg = acc[8 + p2]  + xv[8 + p2];
      float po = acc[12 + p2] + xv[12 + p2];
      float iv = fsig(pi), fv = fsig(pf), gv = ftanhf(pg), o_ = fsig(po);
      float cn = fv * cst[p2] + iv * gv;
      float hn = o_ * ftanhf(cn);
      if (valid) { cst[p2] = cn; hst[p2] = hn; }
      ov[p2] = valid ? hst[p2] : 0.f;
    }

    // carried state -> hbuf[p^1] at [k8=tau][batch][hi*4 .. +3]
    f16x4 hw;
#pragma unroll
    for (int p2 = 0; p2 < 4; ++p2) hw[p2] = (_Float16)hst[p2];
    *reinterpret_cast<f16x4*>(hb + (size_t)(p ^ 1) * (BB * HH) +
                              ((size_t)tau * BB + batch) * 8 + hi * 4) = hw;

    const size_t obase = ((size_t)batch * TT + t) * 1024 + dir * HH + jb;

    if (s < TT - 1) {
      // -- drain h-store (and last step's in-flight outputs/xg), release --
      __syncthreads();
      if (tid == 0)
        __hip_atomic_store(&flg[wg], (unsigned int)(s + 2), __ATOMIC_RELEASE,
                           __HIP_MEMORY_SCOPE_AGENT);

      // -- off-critical-path work: fly during the poll window --
      if (o16) {
        f16x4 ow;
#pragma unroll
        for (int p2 = 0; p2 < 4; ++p2) ow[p2] = (_Float16)ov[p2];
        *reinterpret_cast<f16x4*>(o16 + obase) = ow;
      }
      if (o32) {
        f32x4 ow = {ov[0], ov[1], ov[2], ov[3]};
        *reinterpret_cast<f32x4*>(o32 + obase) = ow;
      }
      float xn[16];
      LOAD_XV(dir ? TT - 2 - s : s + 1, xn);

      // -- relaxed poll (wave 0 only) --
      if (tid < 64) {
        const unsigned int target = (unsigned int)(s + 2);
        unsigned int v = target;
        for (;;) {
          if (tid < 32)
            v = __hip_atomic_load(&flg[tid], __ATOMIC_RELAXED,
                                  __HIP_MEMORY_SCOPE_AGENT);
          if (__all(v >= target)) break;
          __builtin_amdgcn_s_sleep(1);
        }
      }
      // raw barrier: NO vmcnt drain here (outputs/xg stay in flight);
      // "memory" clobber blocks hoisting next step's h-loads above it
      asm volatile("s_barrier" ::: "memory");
      // acquire fence by EVERY wave: each wave invalidates caches for its
      // own subsequent h-loads (no cross-wave inv-visibility assumption)
      __builtin_amdgcn_fence(__ATOMIC_ACQUIRE, "agent");
#pragma unroll
      for (int i = 0; i < 16; ++i) xv[i] = xn[i];
    } else {
      // final step: just store outputs; kernel end drains
      if (o16) {
        f16x4 ow;
#pragma unroll
        for (int p2 = 0; p2 < 4; ++p2) ow[p2] = (_Float16)ov[p2];
        *reinterpret_cast<f16x4*>(o16 + obase) = ow;
      }
      if (o32) {
        f32x4 ow = {ov[0], ov[1], ov[2], ov[3]};
        *reinterpret_cast<f32x4*>(o32 + obase) = ow;
      }
    }
  }
#undef LOAD_XV
}

// --------------------------------------------------------------------------
extern "C" void kernel_launch(void* const* d_in, const int* in_sizes, int n_in,
                              void* d_out, int out_size, void* d_ws,
                              size_t ws_size, hipStream_t stream) {
  (void)in_sizes; (void)n_in; (void)out_size; (void)ws_size;

  const float* hidden = (const float*)d_in[0];
  const int* seqlen   = (const int*)d_in[1];
  const float* wih[6]; const float* whh[6]; const float* bias[6];
  for (int l = 0; l < 3; ++l)
    for (int d = 0; d < 2; ++d) {
      int base = 2 + l * 6 + d * 3;
      wih[l * 2 + d]  = (const float*)d_in[base + 0];
      whh[l * 2 + d]  = (const float*)d_in[base + 1];
      bias[l * 2 + d] = (const float*)d_in[base + 2];
    }

  // workspace layout (~428 MB total)
  char* ws = (char*)d_ws;
  unsigned int* flags = (unsigned int*)ws;                       // 4 KB
  _Float16* hbuf  = (_Float16*)(ws + 4096);                      // 256 KB
  _Float16* wih16 = (_Float16*)(ws + 4096 + 262144);             // 24 MB
  _Float16* xA    = (_Float16*)(ws + 4096 + 262144 + 25165824);  // 64 MB
  _Float16* xB    = xA + (size_t)BB * TT * DK;                   // 64 MB
  _Float16* xgF   = xB + (size_t)BB * TT * DK;                   // 128 MB
  _Float16* xgB   = xgF + (size_t)TT * G4 * BB;                  // 128 MB

  hipMemsetAsync(flags, 0, 4096, stream);

  // converts: hidden -> xA fp16 (layout preserved [b][t][d]); w_ih -> fp16
  k_cvt<<<(BB * TT * DK / 4) / 256, 256, 0, stream>>>(hidden, xA,
                                                      BB * TT * DK / 4);
  for (int i = 0; i < 6; ++i)
    k_cvt<<<(G4 * DK / 4) / 256, 256, 0, stream>>>(
        wih[i], wih16 + (size_t)i * G4 * DK, G4 * DK / 4);

  const _Float16* Xl = xA;
  _Float16* outs[3] = {xB, xA, nullptr};
  for (int l = 0; l < 3; ++l) {
    k_gemm<<<dim3(BB * TT / 128, G4 / 128, 2), 256, 0, stream>>>(
        Xl, wih16 + (size_t)(2 * l) * G4 * DK,
        wih16 + (size_t)(2 * l + 1) * G4 * DK, bias[2 * l], bias[2 * l + 1],
        xgF, xgB);
    k_rec<<<dim3(64), 256, 0, stream>>>(
        whh[2 * l], whh[2 * l + 1], xgF, xgB, seqlen, hbuf, flags + l * 128,
        outs[l], (l == 2) ? (float*)d_out : nullptr);
    Xl = outs[l];
  }
}

// Round 7
// 8331.930 us; speedup vs baseline: 1.7609x; 1.7609x over previous
//
#include <hip/hip_runtime.h>

// ===========================================================================
// VariationalLSTM: 3-layer bidirectional masked LSTM, B=64 T=512 Din=1024 H=512
//
//  k_cvt : fp32->fp16 elementwise converts (hidden, w_ih weights)
//  k_gemm: xg = X @ W_ih^T + bias  (fp16 MFMA 16x16x32, 128x128 tile,
//          global_load_lds staging; output layout [t][gatecol][batch] fp16)
//  k_rec : persistent bidirectional recurrence, 64 wgs (32/dir).
//          w_hh lives in VGPRs (32 x f16x8 per lane); per step one
//          mfma_32x32x16_f16 tile per wave, permuted gate rows so the
//          LSTM cell is lane-local (4 gates x 4 j for one batch).
//          FENCE-FREE cross-wg sync (NO buffer_wbl2 / buffer_inv in loop):
//          all hbuf/flag traffic uses sc0 sc1 (MALL-coherent, bypasses the
//          non-coherent per-XCD L2s). Step: h-store(sc) -> vmcnt(0) ->
//          s_barrier -> relaxed flag store(sc1) -> outputs+xg prefetch fly
//          during relaxed poll -> s_barrier -> h-loads(sc) staged
//          vmcnt(16)/vmcnt(0) overlapping MFMA.
// ===========================================================================

#define TT 512
#define BB 64
#define HH 512
#define G4 2048
#define DK 1024

#define AS1 __attribute__((address_space(1)))
#define AS3 __attribute__((address_space(3)))

typedef float   f32x4  __attribute__((ext_vector_type(4)));
typedef float   f32x16 __attribute__((ext_vector_type(16)));
typedef _Float16 f16x8 __attribute__((ext_vector_type(8)));
typedef _Float16 f16x4 __attribute__((ext_vector_type(4)));

__device__ __forceinline__ float fsig(float x) {
  return 1.0f / (1.0f + __expf(-x));
}
__device__ __forceinline__ float ftanhf(float x) {
  float a = fabsf(x);
  float e = __expf(-2.0f * a);
  float r = (1.0f - e) / (1.0f + e);
  return x < 0.f ? -r : r;
}

// --------------------------------------------------------------------------
// fp32 -> fp16 convert (vectorized 4-wide)
// --------------------------------------------------------------------------
__global__ __launch_bounds__(256) void k_cvt(const float* __restrict__ src,
                                             _Float16* __restrict__ dst,
                                             int n4) {
  int i = blockIdx.x * 256 + threadIdx.x;
  if (i >= n4) return;
  float4 v = reinterpret_cast<const float4*>(src)[i];
  f16x4 o;
  o[0] = (_Float16)v.x; o[1] = (_Float16)v.y;
  o[2] = (_Float16)v.z; o[3] = (_Float16)v.w;
  reinterpret_cast<f16x4*>(dst)[i] = o;
}

// --------------------------------------------------------------------------
// xg GEMM: C[m=t*64+b][n=gatecol] = X[m][k] * W[n][k] + bias[n]
// X stored [b][t][k] fp16 (row b*TT+t). Output fp16 [t][n][b].
// 128x128 tile, BK=32, 4 waves (2x2), 16x16x32 MFMA, 4x4 acc per wave.
// --------------------------------------------------------------------------
__global__ __launch_bounds__(256) void k_gemm(
    const _Float16* __restrict__ X,
    const _Float16* __restrict__ Wf, const _Float16* __restrict__ Wb,
    const float* __restrict__ bf, const float* __restrict__ bb,
    _Float16* __restrict__ of, _Float16* __restrict__ ob) {
  const _Float16* W   = blockIdx.z ? Wb : Wf;
  const float* bias   = blockIdx.z ? bb : bf;
  _Float16* out       = blockIdx.z ? ob : of;

  __shared__ _Float16 As[128 * 32];
  __shared__ _Float16 Bs[128 * 32];

  const int tid  = threadIdx.x;
  const int wave = tid >> 6;
  const int lane = tid & 63;
  const int m0 = blockIdx.x * 128;
  const int n0 = blockIdx.y * 128;
  const int wm = (wave & 1) * 64;
  const int wn = (wave >> 1) * 64;
  const int fr = lane & 15;
  const int ko = (lane >> 4) * 8;

  const int srow = wave * 16 + (lane >> 2);  // staged row within 64-chunk
  const int skh  = (lane & 3) * 8;           // k half-offset within 32

  const f32x4 z4 = {0.f, 0.f, 0.f, 0.f};
  f32x4 acc[4][4];
#pragma unroll
  for (int i = 0; i < 4; ++i)
#pragma unroll
    for (int j = 0; j < 4; ++j) acc[i][j] = z4;

  for (int k0 = 0; k0 < DK; k0 += 32) {
    __syncthreads();  // previous iter's LDS reads done
#pragma unroll
    for (int c = 0; c < 2; ++c) {
      int r  = c * 64 + srow;
      int m  = m0 + r;
      int xr = (m & 63) * TT + (m >> 6);  // b*T + t
      __builtin_amdgcn_global_load_lds(
          (const AS1 void*)(X + (size_t)xr * DK + k0 + skh),
          (AS3 void*)(As + (c * 64 + wave * 16) * 32), 16, 0, 0);
      __builtin_amdgcn_global_load_lds(
          (const AS1 void*)(W + (size_t)(n0 + r) * DK + k0 + skh),
          (AS3 void*)(Bs + (c * 64 + wave * 16) * 32), 16, 0, 0);
    }
    __syncthreads();
    f16x8 a[4], b[4];
#pragma unroll
    for (int i = 0; i < 4; ++i)
      a[i] = *reinterpret_cast<const f16x8*>(As + (wm + i * 16 + fr) * 32 + ko);
#pragma unroll
    for (int i = 0; i < 4; ++i)
      b[i] = *reinterpret_cast<const f16x8*>(Bs + (wn + i * 16 + fr) * 32 + ko);
#pragma unroll
    for (int mi = 0; mi < 4; ++mi)
#pragma unroll
      for (int ni = 0; ni < 4; ++ni)
        acc[mi][ni] = __builtin_amdgcn_mfma_f32_16x16x32_f16(
            a[mi], b[ni], acc[mi][ni], 0, 0, 0);
  }

  // epilogue: out[t][col][b] fp16, + bias
  const int t = (m0 + wm) >> 6;  // uniform per wave (wm multiple of 64)
#pragma unroll
  for (int ni = 0; ni < 4; ++ni) {
    const int col  = n0 + wn + ni * 16 + fr;
    const float bv = bias[col];
#pragma unroll
    for (int mi = 0; mi < 4; ++mi) {
      const int bl = mi * 16 + (lane >> 4) * 4;  // batch base (+reg)
      f16x4 o;
      o[0] = (_Float16)(acc[mi][ni][0] + bv);
      o[1] = (_Float16)(acc[mi][ni][1] + bv);
      o[2] = (_Float16)(acc[mi][ni][2] + bv);
      o[3] = (_Float16)(acc[mi][ni][3] + bv);
      *reinterpret_cast<f16x4*>(out + ((size_t)t * G4 + col) * BB + bl) = o;
    }
  }
}

// --------------------------------------------------------------------------
// full fenced global barrier — used ONCE at init (its release wbl2 also
// flushes the hbuf zero-init to MALL)
// --------------------------------------------------------------------------
__device__ __forceinline__ void gbar(unsigned int* flg, int wg,
                                     unsigned int target) {
  __syncthreads();
  int tid = threadIdx.x;
  if (tid < 64) {
    if (tid == 0)
      __hip_atomic_store(&flg[wg], target, __ATOMIC_RELEASE,
                         __HIP_MEMORY_SCOPE_AGENT);
    unsigned int v = target;
    for (;;) {
      if (tid < 32)
        v = __hip_atomic_load(&flg[tid], __ATOMIC_ACQUIRE,
                              __HIP_MEMORY_SCOPE_AGENT);
      if (__all(v >= target)) break;
      __builtin_amdgcn_s_sleep(1);
    }
  }
  __syncthreads();
}

// --------------------------------------------------------------------------
// persistent bidirectional recurrence for one layer
// hbuf layout: [dir][buf p][k8 = k/8][batch][k&7] fp16; ALL hbuf accesses
// use sc0 sc1 (MALL-coherent) -> no cache-maintenance ops needed.
// --------------------------------------------------------------------------
__global__ __launch_bounds__(256, 1) void k_rec(
    const float* __restrict__ whf, const float* __restrict__ whb,
    const _Float16* __restrict__ xgf, const _Float16* __restrict__ xgb,
    const int* __restrict__ seqlen,
    _Float16* __restrict__ hbuf,       // [2 dir][2 buf][HH/8][BB][8] fp16
    unsigned int* __restrict__ flags,  // [2 dir][64] u32
    _Float16* __restrict__ o16,        // [BB][TT][1024] fp16 or null
    float* __restrict__ o32) {         // [BB][TT][1024] fp32 or null
  const int wg  = blockIdx.x & 31;
  const int dir = blockIdx.x >> 5;
  const float* whh    = dir ? whb : whf;
  const _Float16* xg  = dir ? xgb : xgf;
  _Float16* hb        = hbuf + (size_t)dir * (2 * BB * HH);
  unsigned int* flg   = flags + dir * 64;

  const int tid   = threadIdx.x;
  const int wave  = tid >> 6;
  const int lane  = tid & 63;
  const int tau   = wg * 2 + (wave & 1);  // 8-wide j-slice index (0..63)
  const int btile = wave >> 1;            // 0/1 -> batches 0..31 / 32..63
  const int mrow  = lane & 31;            // A-frag row in 32-tile (perm space)
  const int hi    = lane >> 5;
  const int batch = btile * 32 + mrow;    // B-frag / acc-col batch
  // perm row -> w_hh row: gate = mrow>>3, jj = mrow&7
  const int wrow  = (mrow >> 3) * HH + tau * 8 + (mrow & 7);
  const int jb    = tau * 8 + hi * 4;     // this lane's 4 output j columns

  // ---- load w_hh fragments into registers (fp32 -> fp16), 128 VGPRs ----
  f16x8 wfrag[32];
#pragma unroll
  for (int kk = 0; kk < 32; ++kk) {
    const float* s = whh + (size_t)wrow * HH + kk * 16 + hi * 8;
    f16x8 w;
#pragma unroll
    for (int i = 0; i < 8; ++i) w[i] = (_Float16)s[i];
    wfrag[kk] = w;
  }

  const int sl = seqlen[batch];

  // zero hbuf[dir][0] (flushed to MALL by gbar's release below)
  reinterpret_cast<unsigned long long*>(hb)[wg * 256 + tid] = 0ull;

  float cst[4] = {0.f, 0.f, 0.f, 0.f};
  float hst[4] = {0.f, 0.f, 0.f, 0.f};

  // xg slice loader: xv[q*4+p2] = xg[t][q*HH + jb + p2][batch]
  float xv[16];
#define LOAD_XV(tt, dst)                                                     \
  {                                                                          \
    const _Float16* xgt = xg + (size_t)(tt) * (G4 * BB) + batch;             \
    _Pragma("unroll") for (int q = 0; q < 4; ++q)                            \
        _Pragma("unroll") for (int p2 = 0; p2 < 4; ++p2)                     \
            dst[q * 4 + p2] = (float)xgt[(size_t)(q * HH + jb + p2) * BB];   \
  }

  LOAD_XV(dir ? TT - 1 : 0, xv);
  gbar(flg, wg, 1u);

  for (int s = 0; s < TT; ++s) {
    const int t = dir ? (TT - 1 - s) : s;
    const int p = s & 1;

    // ---- h-loads: MALL-coherent (sc0 sc1), 32 x 16B in flight ----
    const _Float16* hbp = hb + (size_t)p * (BB * HH) + (size_t)batch * 8 +
                          (size_t)hi * (BB * 8);
    f16x8 hreg[32];
#pragma unroll
    for (int kk = 0; kk < 32; ++kk)
      asm volatile("global_load_dwordx4 %0, %1, off sc0 sc1"
                   : "=&v"(hreg[kk])
                   : "v"(hbp + (size_t)kk * (2 * BB * 8))
                   : "memory");

    // recurrent GEMM: acc[gaterow][batch] over K=512 (two chains);
    // first 16 MFMAs overlap the tail 16 loads' MALL latency
    f32x16 acc0 = {0.f,0.f,0.f,0.f,0.f,0.f,0.f,0.f,
                   0.f,0.f,0.f,0.f,0.f,0.f,0.f,0.f};
    f32x16 acc1 = {0.f,0.f,0.f,0.f,0.f,0.f,0.f,0.f,
                   0.f,0.f,0.f,0.f,0.f,0.f,0.f,0.f};
    asm volatile("s_waitcnt vmcnt(16)" ::: "memory");  // oldest 16 done
    __builtin_amdgcn_sched_barrier(0);
#pragma unroll
    for (int kk = 0; kk < 16; kk += 2) {
      acc0 = __builtin_amdgcn_mfma_f32_32x32x16_f16(wfrag[kk], hreg[kk], acc0, 0, 0, 0);
      acc1 = __builtin_amdgcn_mfma_f32_32x32x16_f16(wfrag[kk + 1], hreg[kk + 1], acc1, 0, 0, 0);
    }
    asm volatile("s_waitcnt vmcnt(0)" ::: "memory");
    __builtin_amdgcn_sched_barrier(0);
#pragma unroll
    for (int kk = 16; kk < 32; kk += 2) {
      acc0 = __builtin_amdgcn_mfma_f32_32x32x16_f16(wfrag[kk], hreg[kk], acc0, 0, 0, 0);
      acc1 = __builtin_amdgcn_mfma_f32_32x32x16_f16(wfrag[kk + 1], hreg[kk + 1], acc1, 0, 0, 0);
    }
    f32x16 acc = acc0 + acc1;

    // ---- LSTM cell (lane-local: 4 gates x 4 j for one batch) ----
    const bool valid = t < sl;
    float ov[4];
#pragma unroll
    for (int p2 = 0; p2 < 4; ++p2) {
      float pi = acc[p2]      + xv[p2];
      float pf = acc[4 + p2]  + xv[4 + p2];
      float pg = acc[8 + p2]  + xv[8 + p2];
      float po = acc[12 + p2] + xv[12 + p2];
      float iv = fsig(pi), fv = fsig(pf), gv = ftanhf(pg), o_ = fsig(po);
      float cn = fv * cst[p2] + iv * gv;
      float hn = o_ * ftanhf(cn);
      if (valid) { cst[p2] = cn; hst[p2] = hn; }
      ov[p2] = valid ? hst[p2] : 0.f;
    }

    // carried state -> hbuf[p^1]: MALL-coherent write-through (sc0 sc1)
    f16x4 hw;
#pragma unroll
    for (int p2 = 0; p2 < 4; ++p2) hw[p2] = (_Float16)hst[p2];
    {
      _Float16* hdst = hb + (size_t)(p ^ 1) * (BB * HH) +
                       ((size_t)tau * BB + batch) * 8 + hi * 4;
      asm volatile("global_store_dwordx2 %0, %1, off sc0 sc1"
                   :: "v"(hdst), "v"(hw) : "memory");
    }

    const size_t obase = ((size_t)batch * TT + t) * 1024 + dir * HH + jb;

    if (s < TT - 1) {
      // h-store acked at MALL, then wg-wide rendezvous (raw, no L2 ops)
      asm volatile("s_waitcnt vmcnt(0)" ::: "memory");
      asm volatile("s_barrier" ::: "memory");
      // relaxed flag release (sc1 store, NO buffer_wbl2)
      if (tid == 0)
        __hip_atomic_store(&flg[wg], (unsigned int)(s + 2), __ATOMIC_RELAXED,
                           __HIP_MEMORY_SCOPE_AGENT);

      // off-critical-path: outputs + next xg fly during the poll window
      if (o16) {
        f16x4 ow;
#pragma unroll
        for (int p2 = 0; p2 < 4; ++p2) ow[p2] = (_Float16)ov[p2];
        *reinterpret_cast<f16x4*>(o16 + obase) = ow;
      }
      if (o32) {
        f32x4 ow = {ov[0], ov[1], ov[2], ov[3]};
        *reinterpret_cast<f32x4*>(o32 + obase) = ow;
      }
      float xn[16];
      LOAD_XV(dir ? TT - 2 - s : s + 1, xn);

      // relaxed poll (wave 0), NO acquire fence: h-loads are sc-coherent
      if (tid < 64) {
        const unsigned int target = (unsigned int)(s + 2);
        unsigned int v = target;
        for (;;) {
          if (tid < 32)
            v = __hip_atomic_load(&flg[tid], __ATOMIC_RELAXED,
                                  __HIP_MEMORY_SCOPE_AGENT);
          if (__all(v >= target)) break;
          __builtin_amdgcn_s_sleep(1);
        }
      }
      asm volatile("s_barrier" ::: "memory");
#pragma unroll
      for (int i = 0; i < 16; ++i) xv[i] = xn[i];
    } else {
      // final step: outputs only; kernel end drains/flushes
      if (o16) {
        f16x4 ow;
#pragma unroll
        for (int p2 = 0; p2 < 4; ++p2) ow[p2] = (_Float16)ov[p2];
        *reinterpret_cast<f16x4*>(o16 + obase) = ow;
      }
      if (o32) {
        f32x4 ow = {ov[0], ov[1], ov[2], ov[3]};
        *reinterpret_cast<f32x4*>(o32 + obase) = ow;
      }
    }
  }
#undef LOAD_XV
}

// --------------------------------------------------------------------------
extern "C" void kernel_launch(void* const* d_in, const int* in_sizes, int n_in,
                              void* d_out, int out_size, void* d_ws,
                              size_t ws_size, hipStream_t stream) {
  (void)in_sizes; (void)n_in; (void)out_size; (void)ws_size;

  const float* hidden = (const float*)d_in[0];
  const int* seqlen   = (const int*)d_in[1];
  const float* wih[6]; const float* whh[6]; const float* bias[6];
  for (int l = 0; l < 3; ++l)
    for (int d = 0; d < 2; ++d) {
      int base = 2 + l * 6 + d * 3;
      wih[l * 2 + d]  = (const float*)d_in[base + 0];
      whh[l * 2 + d]  = (const float*)d_in[base + 1];
      bias[l * 2 + d] = (const float*)d_in[base + 2];
    }

  // workspace layout (~428 MB total)
  char* ws = (char*)d_ws;
  unsigned int* flags = (unsigned int*)ws;                       // 4 KB
  _Float16* hbuf  = (_Float16*)(ws + 4096);                      // 256 KB
  _Float16* wih16 = (_Float16*)(ws + 4096 + 262144);             // 24 MB
  _Float16* xA    = (_Float16*)(ws + 4096 + 262144 + 25165824);  // 64 MB
  _Float16* xB    = xA + (size_t)BB * TT * DK;                   // 64 MB
  _Float16* xgF   = xB + (size_t)BB * TT * DK;                   // 128 MB
  _Float16* xgB   = xgF + (size_t)TT * G4 * BB;                  // 128 MB

  hipMemsetAsync(flags, 0, 4096, stream);

  // converts: hidden -> xA fp16 (layout preserved [b][t][d]); w_ih -> fp16
  k_cvt<<<(BB * TT * DK / 4) / 256, 256, 0, stream>>>(hidden, xA,
                                                      BB * TT * DK / 4);
  for (int i = 0; i < 6; ++i)
    k_cvt<<<(G4 * DK / 4) / 256, 256, 0, stream>>>(
        wih[i], wih16 + (size_t)i * G4 * DK, G4 * DK / 4);

  const _Float16* Xl = xA;
  _Float16* outs[3] = {xB, xA, nullptr};
  for (int l = 0; l < 3; ++l) {
    k_gemm<<<dim3(BB * TT / 128, G4 / 128, 2), 256, 0, stream>>>(
        Xl, wih16 + (size_t)(2 * l) * G4 * DK,
        wih16 + (size_t)(2 * l + 1) * G4 * DK, bias[2 * l], bias[2 * l + 1],
        xgF, xgB);
    k_rec<<<dim3(64), 256, 0, stream>>>(
        whh[2 * l], whh[2 * l + 1], xgF, xgB, seqlen, hbuf, flags + l * 128,
        outs[l], (l == 2) ? (float*)d_out : nullptr);
    Xl = outs[l];
  }
}